// Round 3
// baseline (451.880 us; speedup 1.0000x reference)
//
#include <hip/hip_runtime.h>

#define IN_F 256
#define OU_F 64
#define BKN 128          // nodes per bucket
#define BSHIFT 7
#define CHUNK 4096       // edges per partition block

// ---------------- GEMM: hp = h @ W (fp32, unchanged) ----------------
__global__ void __launch_bounds__(256, 4)
gemm_kernel(const float* __restrict__ h, const float* __restrict__ W,
            float* __restrict__ hp, int N)
{
    __shared__ float hs[16][IN_F];
    __shared__ float ps[4][16][OU_F];
    const int tid = threadIdx.x;
    const int f   = tid & 63;
    const int kq  = tid >> 6;

    float w[64];
#pragma unroll
    for (int j = 0; j < 64; ++j)
        w[j] = W[(kq * 64 + j) * OU_F + f];

    for (int r0 = blockIdx.x * 16; r0 < N; r0 += gridDim.x * 16) {
#pragma unroll
        for (int q = 0; q < 4; ++q) {
            int idx = tid + q * 256;
            int r = idx >> 6, c4 = idx & 63;
            float4 v = make_float4(0.f, 0.f, 0.f, 0.f);
            if (r0 + r < N)
                v = reinterpret_cast<const float4*>(h)[(size_t)(r0 + r) * (IN_F / 4) + c4];
            reinterpret_cast<float4*>(&hs[r][0])[c4] = v;
        }
        __syncthreads();

        float acc[16];
#pragma unroll
        for (int r = 0; r < 16; ++r) acc[r] = 0.f;

#pragma unroll
        for (int j4 = 0; j4 < 16; ++j4) {
            const float wx = w[j4 * 4 + 0], wy = w[j4 * 4 + 1];
            const float wz = w[j4 * 4 + 2], ww = w[j4 * 4 + 3];
#pragma unroll
            for (int r = 0; r < 16; ++r) {
                float4 hv = *reinterpret_cast<const float4*>(&hs[r][kq * 64 + j4 * 4]);
                acc[r] = fmaf(hv.x, wx, acc[r]);
                acc[r] = fmaf(hv.y, wy, acc[r]);
                acc[r] = fmaf(hv.z, wz, acc[r]);
                acc[r] = fmaf(hv.w, ww, acc[r]);
            }
        }

#pragma unroll
        for (int r = 0; r < 16; ++r) ps[kq][r][f] = acc[r];
        __syncthreads();

#pragma unroll
        for (int q = 0; q < 4; ++q) {
            int e = tid + q * 256;
            int r = e >> 6, ff = e & 63;
            if (r0 + r < N)
                hp[(size_t)(r0 + r) * OU_F + ff] =
                    ps[0][r][ff] + ps[1][r][ff] + ps[2][r][ff] + ps[3][r][ff];
        }
    }
}

// ---------------- bucket histogram ----------------
__global__ void __launch_bounds__(256)
hist_kernel(const int* __restrict__ col, int* __restrict__ bcnt, int E, int NB)
{
    __shared__ int lh[512];
    const int t = threadIdx.x;
    lh[t] = 0; lh[t + 256] = 0;
    __syncthreads();
    const int n4 = E >> 2;
    const int4* c4 = (const int4*)col;
    for (int i = blockIdx.x * 256 + t; i < n4; i += gridDim.x * 256) {
        int4 v = c4[i];
        atomicAdd(&lh[v.x >> BSHIFT], 1);
        atomicAdd(&lh[v.y >> BSHIFT], 1);
        atomicAdd(&lh[v.z >> BSHIFT], 1);
        atomicAdd(&lh[v.w >> BSHIFT], 1);
    }
    if (blockIdx.x == 0)
        for (int e = (n4 << 2) + t; e < E; e += 256)
            atomicAdd(&lh[col[e] >> BSHIFT], 1);
    __syncthreads();
    for (int i = t; i < NB; i += 256)
        if (lh[i]) atomicAdd(&bcnt[i], lh[i]);
}

// ---------------- exclusive scan of <=512 bucket counts (1 block) ----------------
__global__ void __launch_bounds__(256)
scan_kernel(const int* __restrict__ bcnt, int* __restrict__ boffs,
            int* __restrict__ bcursor, int NB)
{
    __shared__ int c[512];
    __shared__ int s[256];
    const int t = threadIdx.x;
    c[t]       = (t < NB)       ? bcnt[t] : 0;
    c[t + 256] = (t + 256 < NB) ? bcnt[t + 256] : 0;
    __syncthreads();
    s[t] = c[2 * t] + c[2 * t + 1];
    __syncthreads();
    for (int d = 1; d < 256; d <<= 1) {
        int v = (t >= d) ? s[t - d] : 0;
        __syncthreads();
        s[t] += v;
        __syncthreads();
    }
    int excl = (t > 0) ? s[t - 1] : 0;
    int e0 = excl;
    int e1 = excl + c[2 * t];
    if (2 * t < NB)     { boffs[2 * t]     = e0; bcursor[2 * t]     = e0; }
    if (2 * t + 1 < NB) { boffs[2 * t + 1] = e1; bcursor[2 * t + 1] = e1; }
    if (t == 255) boffs[NB] = s[255];
}

// ---------------- partition: counting-sort edges into buckets, coalesced writes ----------------
__global__ void __launch_bounds__(256)
partition_kernel(const int* __restrict__ row, const int* __restrict__ col,
                 const float* __restrict__ vals, int* __restrict__ bcursor,
                 int2* __restrict__ epk, int E, int NB)
{
    __shared__ int  hist[512];
    __shared__ int  X[512];        // local excl scan, then running cursor
    __shared__ int  gshift[512];   // global base - local base
    __shared__ int  s[256];
    __shared__ int2 stage[CHUNK];  // 32 KB
    __shared__ int  gpos[CHUNK];   // 16 KB

    const int t = threadIdx.x;
    const int base = blockIdx.x * CHUNK;
    const int n = min(CHUNK, E - base);

    hist[t] = 0; hist[t + 256] = 0;
    __syncthreads();

#pragma unroll
    for (int k = 0; k < 16; ++k) {
        int i = t + k * 256;
        if (i < n) atomicAdd(&hist[col[base + i] >> BSHIFT], 1);
    }
    __syncthreads();

    s[t] = hist[2 * t] + hist[2 * t + 1];
    __syncthreads();
    for (int d = 1; d < 256; d <<= 1) {
        int v = (t >= d) ? s[t - d] : 0;
        __syncthreads();
        s[t] += v;
        __syncthreads();
    }
    int excl = (t > 0) ? s[t - 1] : 0;
    X[2 * t]     = excl;
    X[2 * t + 1] = excl + hist[2 * t];
    __syncthreads();

    for (int i = t; i < NB; i += 256) {
        int hcnt = hist[i];
        int g = hcnt ? atomicAdd(&bcursor[i], hcnt) : 0;
        gshift[i] = g - X[i];
    }
    __syncthreads();

#pragma unroll
    for (int k = 0; k < 16; ++k) {
        int i = t + k * 256;
        if (i < n) {
            int e  = base + i;
            int cv = col[e];
            int b  = cv >> BSHIFT;
            int r  = atomicAdd(&X[b], 1);
            unsigned pk = (unsigned)row[e] | ((unsigned)(cv & (BKN - 1)) << 17);
            stage[r] = make_int2((int)pk, __float_as_int(vals[e]));
            gpos[r]  = gshift[b] + r;
        }
    }
    __syncthreads();

#pragma unroll
    for (int k = 0; k < 16; ++k) {
        int i = t + k * 256;
        if (i < n) epk[gpos[i]] = stage[i];   // runs of consecutive addresses
    }
}

// ---------------- aggregate: one block per bucket, LDS accumulators ----------------
__global__ void __launch_bounds__(512)
aggregate_kernel(const float* __restrict__ hp, const int* __restrict__ boffs,
                 const int2* __restrict__ epk, float* __restrict__ out, int N)
{
    __shared__ float acc[BKN * OU_F];   // 32 KB
    const int t    = threadIdx.x;
    const int lane = t & 63;
    const int wid  = t >> 6;            // 0..7
    const int b    = blockIdx.x;
    const int node0 = b << BSHIFT;

#pragma unroll
    for (int i = 0; i < 16; ++i) acc[t + i * 512] = 0.f;
    __syncthreads();

    const int s = boffs[b];
    const int e = boffs[b + 1];

    for (int base = s + (wid << 6); base < e; base += 8 * 64) {
        const int n = min(64, e - base);
        int2 m = make_int2(0, 0);
        if (lane < n) m = epk[base + lane];
        int j = 0;
        for (; j + 4 <= n; j += 4) {
            unsigned p0 = (unsigned)__shfl(m.x, j);
            unsigned p1 = (unsigned)__shfl(m.x, j + 1);
            unsigned p2 = (unsigned)__shfl(m.x, j + 2);
            unsigned p3 = (unsigned)__shfl(m.x, j + 3);
            float v0 = __int_as_float(__shfl(m.y, j));
            float v1 = __int_as_float(__shfl(m.y, j + 1));
            float v2 = __int_as_float(__shfl(m.y, j + 2));
            float v3 = __int_as_float(__shfl(m.y, j + 3));
            float x0 = hp[((p0 & 0x1FFFFu) << 6) + lane];
            float x1 = hp[((p1 & 0x1FFFFu) << 6) + lane];
            float x2 = hp[((p2 & 0x1FFFFu) << 6) + lane];
            float x3 = hp[((p3 & 0x1FFFFu) << 6) + lane];
            atomicAdd(&acc[((p0 >> 17) << 6) + lane], v0 * x0);
            atomicAdd(&acc[((p1 >> 17) << 6) + lane], v1 * x1);
            atomicAdd(&acc[((p2 >> 17) << 6) + lane], v2 * x2);
            atomicAdd(&acc[((p3 >> 17) << 6) + lane], v3 * x3);
        }
        for (; j < n; ++j) {
            unsigned p = (unsigned)__shfl(m.x, j);
            float    v = __int_as_float(__shfl(m.y, j));
            float    x = hp[((p & 0x1FFFFu) << 6) + lane];
            atomicAdd(&acc[((p >> 17) << 6) + lane], v * x);
        }
    }
    __syncthreads();

#pragma unroll
    for (int i = 0; i < 16; ++i) {
        int idx  = t + i * 512;
        int node = node0 + (idx >> 6);
        if (node < N) out[(size_t)node * OU_F + (idx & 63)] = acc[idx];
    }
}

// ---------------- fallback (atomic scatter) ----------------
__global__ void __launch_bounds__(256)
scatter_kernel(const float* __restrict__ hp, const int* __restrict__ row,
               const int* __restrict__ col, const float* __restrict__ vals,
               float* __restrict__ out, int E)
{
    unsigned int gid = blockIdx.x * 256u + threadIdx.x;
    int e = (int)(gid >> 6);
    if (e >= E) return;
    int f = (int)(gid & 63u);
    int r = row[e], c = col[e];
    float m = vals[e] * hp[(size_t)r * OU_F + f];
    __hip_atomic_fetch_add(&out[(size_t)c * OU_F + f], m,
                           __ATOMIC_RELAXED, __HIP_MEMORY_SCOPE_AGENT);
}

extern "C" void kernel_launch(void* const* d_in, const int* in_sizes, int n_in,
                              void* d_out, int out_size, void* d_ws, size_t ws_size,
                              hipStream_t stream)
{
    const float* h    = (const float*)d_in[0];
    const float* W    = (const float*)d_in[1];
    const int*   row  = (const int*)d_in[2];
    const int*   col  = (const int*)d_in[3];
    const float* vals = (const float*)d_in[4];
    float*       out  = (float*)d_out;

    const int N = in_sizes[0] / IN_F;
    const int E = in_sizes[2];
    const int NB = (N + BKN - 1) / BKN;

    char*  ws  = (char*)d_ws;
    size_t off = 0;
    auto alloc = [&](size_t bytes) -> char* {
        char* p = ws + off;
        off = (off + bytes + 255) & ~(size_t)255;
        return p;
    };
    float* hp      = (float*)alloc((size_t)N * OU_F * 4);
    int*   bcnt    = (int*)  alloc((size_t)NB * 4);
    int*   boffs   = (int*)  alloc((size_t)(NB + 1) * 4);
    int*   bcursor = (int*)  alloc((size_t)NB * 4);
    int2*  epk     = (int2*) alloc((size_t)E * 8);
    const bool fits = (off <= ws_size) && (NB <= 512) && (N < 131072);

    gemm_kernel<<<1024, 256, 0, stream>>>(h, W, hp, N);

    if (fits) {
        hipMemsetAsync(bcnt, 0, (size_t)NB * 4, stream);
        hist_kernel<<<256, 256, 0, stream>>>(col, bcnt, E, NB);
        scan_kernel<<<1, 256, 0, stream>>>(bcnt, boffs, bcursor, NB);
        partition_kernel<<<(E + CHUNK - 1) / CHUNK, 256, 0, stream>>>(
            row, col, vals, bcursor, epk, E, NB);
        aggregate_kernel<<<NB, 512, 0, stream>>>(hp, boffs, epk, out, N);
    } else {
        hipMemsetAsync(d_out, 0, (size_t)out_size * sizeof(float), stream);
        unsigned long long total = (unsigned long long)E * 64ull;
        unsigned int sgrid = (unsigned int)((total + 255ull) / 256ull);
        scatter_kernel<<<sgrid, 256, 0, stream>>>(hp, row, col, vals, out, E);
    }
}

// Round 4
// 119.361 us; speedup vs baseline: 3.7858x; 3.7858x over previous
//
#include <hip/hip_runtime.h>

#define IN_F 256
#define OU_F 64
#define BKN 128          // nodes per bucket
#define BSHIFT 7
#define CHUNK 4096       // edges per partition block
#define STAGE_CAP 4096   // max records staged in LDS by csr_kernel

// ---------------- GEMM: hp = h @ W (fp32, unchanged) ----------------
__global__ void __launch_bounds__(256, 4)
gemm_kernel(const float* __restrict__ h, const float* __restrict__ W,
            float* __restrict__ hp, int N)
{
    __shared__ float hs[16][IN_F];
    __shared__ float ps[4][16][OU_F];
    const int tid = threadIdx.x;
    const int f   = tid & 63;
    const int kq  = tid >> 6;

    float w[64];
#pragma unroll
    for (int j = 0; j < 64; ++j)
        w[j] = W[(kq * 64 + j) * OU_F + f];

    for (int r0 = blockIdx.x * 16; r0 < N; r0 += gridDim.x * 16) {
#pragma unroll
        for (int q = 0; q < 4; ++q) {
            int idx = tid + q * 256;
            int r = idx >> 6, c4 = idx & 63;
            float4 v = make_float4(0.f, 0.f, 0.f, 0.f);
            if (r0 + r < N)
                v = reinterpret_cast<const float4*>(h)[(size_t)(r0 + r) * (IN_F / 4) + c4];
            reinterpret_cast<float4*>(&hs[r][0])[c4] = v;
        }
        __syncthreads();

        float acc[16];
#pragma unroll
        for (int r = 0; r < 16; ++r) acc[r] = 0.f;

#pragma unroll
        for (int j4 = 0; j4 < 16; ++j4) {
            const float wx = w[j4 * 4 + 0], wy = w[j4 * 4 + 1];
            const float wz = w[j4 * 4 + 2], ww = w[j4 * 4 + 3];
#pragma unroll
            for (int r = 0; r < 16; ++r) {
                float4 hv = *reinterpret_cast<const float4*>(&hs[r][kq * 64 + j4 * 4]);
                acc[r] = fmaf(hv.x, wx, acc[r]);
                acc[r] = fmaf(hv.y, wy, acc[r]);
                acc[r] = fmaf(hv.z, wz, acc[r]);
                acc[r] = fmaf(hv.w, ww, acc[r]);
            }
        }

#pragma unroll
        for (int r = 0; r < 16; ++r) ps[kq][r][f] = acc[r];
        __syncthreads();

#pragma unroll
        for (int q = 0; q < 4; ++q) {
            int e = tid + q * 256;
            int r = e >> 6, ff = e & 63;
            if (r0 + r < N)
                hp[(size_t)(r0 + r) * OU_F + ff] =
                    ps[0][r][ff] + ps[1][r][ff] + ps[2][r][ff] + ps[3][r][ff];
        }
    }
}

// ---------------- bucket histogram ----------------
__global__ void __launch_bounds__(256)
hist_kernel(const int* __restrict__ col, int* __restrict__ bcnt, int E, int NB)
{
    __shared__ int lh[512];
    const int t = threadIdx.x;
    lh[t] = 0; lh[t + 256] = 0;
    __syncthreads();
    const int n4 = E >> 2;
    const int4* c4 = (const int4*)col;
    for (int i = blockIdx.x * 256 + t; i < n4; i += gridDim.x * 256) {
        int4 v = c4[i];
        atomicAdd(&lh[v.x >> BSHIFT], 1);
        atomicAdd(&lh[v.y >> BSHIFT], 1);
        atomicAdd(&lh[v.z >> BSHIFT], 1);
        atomicAdd(&lh[v.w >> BSHIFT], 1);
    }
    if (blockIdx.x == 0)
        for (int e = (n4 << 2) + t; e < E; e += 256)
            atomicAdd(&lh[col[e] >> BSHIFT], 1);
    __syncthreads();
    for (int i = t; i < NB; i += 256)
        if (lh[i]) atomicAdd(&bcnt[i], lh[i]);
}

// ---------------- exclusive scan of <=512 bucket counts (1 block) ----------------
__global__ void __launch_bounds__(256)
scan_kernel(const int* __restrict__ bcnt, int* __restrict__ boffs,
            int* __restrict__ bcursor, int NB)
{
    __shared__ int c[512];
    __shared__ int s[256];
    const int t = threadIdx.x;
    c[t]       = (t < NB)       ? bcnt[t] : 0;
    c[t + 256] = (t + 256 < NB) ? bcnt[t + 256] : 0;
    __syncthreads();
    s[t] = c[2 * t] + c[2 * t + 1];
    __syncthreads();
    for (int d = 1; d < 256; d <<= 1) {
        int v = (t >= d) ? s[t - d] : 0;
        __syncthreads();
        s[t] += v;
        __syncthreads();
    }
    int excl = (t > 0) ? s[t - 1] : 0;
    int e0 = excl;
    int e1 = excl + c[2 * t];
    if (2 * t < NB)     { boffs[2 * t]     = e0; bcursor[2 * t]     = e0; }
    if (2 * t + 1 < NB) { boffs[2 * t + 1] = e1; bcursor[2 * t + 1] = e1; }
    if (t == 255) boffs[NB] = s[255];
}

// ---------------- partition: counting-sort edges into buckets, coalesced writes ----------------
__global__ void __launch_bounds__(256)
partition_kernel(const int* __restrict__ row, const int* __restrict__ col,
                 const float* __restrict__ vals, int* __restrict__ bcursor,
                 int2* __restrict__ epk, int E, int NB)
{
    __shared__ int  hist[512];
    __shared__ int  X[512];        // local excl scan, then running cursor
    __shared__ int  gshift[512];   // global base - local base
    __shared__ int  s[256];
    __shared__ int2 stage[CHUNK];  // 32 KB
    __shared__ int  gpos[CHUNK];   // 16 KB

    const int t = threadIdx.x;
    const int base = blockIdx.x * CHUNK;
    const int n = min(CHUNK, E - base);

    hist[t] = 0; hist[t + 256] = 0;
    __syncthreads();

#pragma unroll
    for (int k = 0; k < 16; ++k) {
        int i = t + k * 256;
        if (i < n) atomicAdd(&hist[col[base + i] >> BSHIFT], 1);
    }
    __syncthreads();

    s[t] = hist[2 * t] + hist[2 * t + 1];
    __syncthreads();
    for (int d = 1; d < 256; d <<= 1) {
        int v = (t >= d) ? s[t - d] : 0;
        __syncthreads();
        s[t] += v;
        __syncthreads();
    }
    int excl = (t > 0) ? s[t - 1] : 0;
    X[2 * t]     = excl;
    X[2 * t + 1] = excl + hist[2 * t];
    __syncthreads();

    for (int i = t; i < NB; i += 256) {
        int hcnt = hist[i];
        int g = hcnt ? atomicAdd(&bcursor[i], hcnt) : 0;
        gshift[i] = g - X[i];
    }
    __syncthreads();

#pragma unroll
    for (int k = 0; k < 16; ++k) {
        int i = t + k * 256;
        if (i < n) {
            int e  = base + i;
            int cv = col[e];
            int b  = cv >> BSHIFT;
            int r  = atomicAdd(&X[b], 1);
            unsigned pk = (unsigned)row[e] | ((unsigned)(cv & (BKN - 1)) << 17);
            stage[r] = make_int2((int)pk, __float_as_int(vals[e]));
            gpos[r]  = gshift[b] + r;
        }
    }
    __syncthreads();

#pragma unroll
    for (int k = 0; k < 16; ++k) {
        int i = t + k * 256;
        if (i < n) epk[gpos[i]] = stage[i];   // runs of consecutive addresses
    }
}

// ---------------- within-bucket counting sort by node + CSR offsets ----------------
__global__ void __launch_bounds__(256)
csr_kernel(const int2* __restrict__ epk, const int* __restrict__ boffs,
           int2* __restrict__ epk2, int* __restrict__ node_offs,
           int N, int NB)
{
    __shared__ int  cnt[BKN];
    __shared__ int  sc[BKN];
    __shared__ int  cur[BKN];
    __shared__ int2 stage[STAGE_CAP];   // 32 KB
    const int t = threadIdx.x;
    const int b = blockIdx.x;
    const int s = boffs[b], e = boffs[b + 1];
    const int n = e - s;
    const int node0 = b << BSHIFT;

    if (t < BKN) cnt[t] = 0;
    __syncthreads();
    for (int i = t; i < n; i += 256)
        atomicAdd(&cnt[((unsigned)epk[s + i].x) >> 17], 1);
    __syncthreads();

    if (t < BKN) sc[t] = cnt[t];
    __syncthreads();
    for (int d = 1; d < BKN; d <<= 1) {       // Hillis-Steele inclusive scan
        int v = 0;
        if (t < BKN && t >= d) v = sc[t - d];
        __syncthreads();
        if (t < BKN) sc[t] += v;
        __syncthreads();
    }
    if (t < BKN) {
        int excl = sc[t] - cnt[t];
        cur[t] = excl;
        int node = node0 + t;
        if (node < N) node_offs[node] = s + excl;
    }
    if (b == NB - 1 && t == 0) node_offs[N] = e;
    __syncthreads();

    if (n <= STAGE_CAP) {
        for (int i = t; i < n; i += 256) {
            int2 r = epk[s + i];
            int pos = atomicAdd(&cur[((unsigned)r.x) >> 17], 1);
            stage[pos] = r;
        }
        __syncthreads();
        for (int i = t; i < n; i += 256)
            epk2[s + i] = stage[i];           // fully coalesced
    } else {
        for (int i = t; i < n; i += 256) {
            int2 r = epk[s + i];
            int pos = atomicAdd(&cur[((unsigned)r.x) >> 17], 1);
            epk2[s + pos] = r;                // rare fallback, L2-local region
        }
    }
}

// ---------------- gather: one wave per destination node, no atomics ----------------
__global__ void __launch_bounds__(256)
gather_kernel(const float* __restrict__ hp, const int* __restrict__ node_offs,
              const int2* __restrict__ epk2, float* __restrict__ out, int N)
{
    int wid  = (int)((blockIdx.x * 256u + threadIdx.x) >> 6);   // node id
    int lane = threadIdx.x & 63;                                 // feature id
    if (wid >= N) return;
    int s = node_offs[wid], e = node_offs[wid + 1];
    float acc = 0.f;
    for (int base = s; base < e; base += 64) {
        int n = min(64, e - base);
        int2 m = make_int2(0, 0);
        if (lane < n) m = epk2[base + lane];
        int j = 0;
        for (; j + 4 <= n; j += 4) {
            unsigned r0 = (unsigned)__shfl(m.x, j)     & 0x1FFFFu;
            unsigned r1 = (unsigned)__shfl(m.x, j + 1) & 0x1FFFFu;
            unsigned r2 = (unsigned)__shfl(m.x, j + 2) & 0x1FFFFu;
            unsigned r3 = (unsigned)__shfl(m.x, j + 3) & 0x1FFFFu;
            float v0 = __int_as_float(__shfl(m.y, j));
            float v1 = __int_as_float(__shfl(m.y, j + 1));
            float v2 = __int_as_float(__shfl(m.y, j + 2));
            float v3 = __int_as_float(__shfl(m.y, j + 3));
            float x0 = hp[((size_t)r0 << 6) + lane];
            float x1 = hp[((size_t)r1 << 6) + lane];
            float x2 = hp[((size_t)r2 << 6) + lane];
            float x3 = hp[((size_t)r3 << 6) + lane];
            acc = fmaf(v0, x0, acc);
            acc = fmaf(v1, x1, acc);
            acc = fmaf(v2, x2, acc);
            acc = fmaf(v3, x3, acc);
        }
        for (; j < n; ++j) {
            unsigned r = (unsigned)__shfl(m.x, j) & 0x1FFFFu;
            float    v = __int_as_float(__shfl(m.y, j));
            acc = fmaf(v, hp[((size_t)r << 6) + lane], acc);
        }
    }
    out[(size_t)wid * OU_F + lane] = acc;
}

// ---------------- fallback (atomic scatter) ----------------
__global__ void __launch_bounds__(256)
scatter_kernel(const float* __restrict__ hp, const int* __restrict__ row,
               const int* __restrict__ col, const float* __restrict__ vals,
               float* __restrict__ out, int E)
{
    unsigned int gid = blockIdx.x * 256u + threadIdx.x;
    int e = (int)(gid >> 6);
    if (e >= E) return;
    int f = (int)(gid & 63u);
    int r = row[e], c = col[e];
    float m = vals[e] * hp[(size_t)r * OU_F + f];
    __hip_atomic_fetch_add(&out[(size_t)c * OU_F + f], m,
                           __ATOMIC_RELAXED, __HIP_MEMORY_SCOPE_AGENT);
}

extern "C" void kernel_launch(void* const* d_in, const int* in_sizes, int n_in,
                              void* d_out, int out_size, void* d_ws, size_t ws_size,
                              hipStream_t stream)
{
    const float* h    = (const float*)d_in[0];
    const float* W    = (const float*)d_in[1];
    const int*   row  = (const int*)d_in[2];
    const int*   col  = (const int*)d_in[3];
    const float* vals = (const float*)d_in[4];
    float*       out  = (float*)d_out;

    const int N = in_sizes[0] / IN_F;
    const int E = in_sizes[2];
    const int NB = (N + BKN - 1) / BKN;

    char*  ws  = (char*)d_ws;
    size_t off = 0;
    auto alloc = [&](size_t bytes) -> char* {
        char* p = ws + off;
        off = (off + bytes + 255) & ~(size_t)255;
        return p;
    };
    float* hp        = (float*)alloc((size_t)N * OU_F * 4);
    int*   bcnt      = (int*)  alloc((size_t)NB * 4);
    int*   boffs     = (int*)  alloc((size_t)(NB + 1) * 4);
    int*   bcursor   = (int*)  alloc((size_t)NB * 4);
    int*   node_offs = (int*)  alloc((size_t)(N + 1) * 4);
    int2*  epk       = (int2*) alloc((size_t)E * 8);
    int2*  epk2      = (int2*) alloc((size_t)E * 8);
    const bool fits = (off <= ws_size) && (NB <= 512) && (N < 131072);

    gemm_kernel<<<1024, 256, 0, stream>>>(h, W, hp, N);

    if (fits) {
        hipMemsetAsync(bcnt, 0, (size_t)NB * 4, stream);
        hist_kernel<<<256, 256, 0, stream>>>(col, bcnt, E, NB);
        scan_kernel<<<1, 256, 0, stream>>>(bcnt, boffs, bcursor, NB);
        partition_kernel<<<(E + CHUNK - 1) / CHUNK, 256, 0, stream>>>(
            row, col, vals, bcursor, epk, E, NB);
        csr_kernel<<<NB, 256, 0, stream>>>(epk, boffs, epk2, node_offs, N, NB);
        gather_kernel<<<(N + 3) / 4, 256, 0, stream>>>(hp, node_offs, epk2, out, N);
    } else {
        hipMemsetAsync(d_out, 0, (size_t)out_size * sizeof(float), stream);
        unsigned long long total = (unsigned long long)E * 64ull;
        unsigned int sgrid = (unsigned int)((total + 255ull) / 256ull);
        scatter_kernel<<<sgrid, 256, 0, stream>>>(hp, row, col, vals, out, E);
    }
}

// Round 5
// 89.976 us; speedup vs baseline: 5.0222x; 1.3266x over previous
//
#include <hip/hip_runtime.h>
#include <hip/hip_bf16.h>

#define IN_F 256
#define OU_F 64
#define BKN 128          // nodes per bucket
#define BSHIFT 7
#define CHUNK 4096       // edges per partition block
#define STAGE_CAP 4096   // max records staged in LDS by csr_kernel

typedef __attribute__((ext_vector_type(8))) short short8;
typedef __attribute__((ext_vector_type(4))) float f32x4;

// ---------------- GEMM: hp = h @ W via bf16 MFMA ----------------
// One block per 64-row tile. W staged once per block into LDS, transposed,
// bf16, padded: Wt[col][k], stride 264 (2-way bank alias only).
// Wave w: rows tile*64 + w*16 .. +15. B-frag = 1 ds_read_b128.
// A-frag: 2 float4 global loads/lane + cvt_pk. 8 k-steps x 4 n-tiles MFMA.
__device__ inline short8 cvt8(float4 a, float4 b)
{
    union { short8 s8; __hip_bfloat162 h2[4]; } u;
    u.h2[0] = __float22bfloat162_rn(make_float2(a.x, a.y));
    u.h2[1] = __float22bfloat162_rn(make_float2(a.z, a.w));
    u.h2[2] = __float22bfloat162_rn(make_float2(b.x, b.y));
    u.h2[3] = __float22bfloat162_rn(make_float2(b.z, b.w));
    return u.s8;
}

__global__ void __launch_bounds__(256, 4)
gemm_mfma_kernel(const float* __restrict__ h, const float* __restrict__ W,
                 float* __restrict__ hp, int N)
{
    __shared__ unsigned short Wt[64][264];   // 33792 B, [col][k] bf16
    const int t = threadIdx.x;

    // ---- stage W (256x64 fp32) -> Wt transposed bf16, packed 2-per-write ----
#pragma unroll
    for (int i = 0; i < 32; ++i) {
        int p  = t + i * 256;          // 8192 (col, k-pair) slots
        int c  = p & 63;
        int k0 = (p >> 6) << 1;
        float x = W[(size_t)k0 * OU_F + c];
        float y = W[(size_t)(k0 + 1) * OU_F + c];
        __hip_bfloat162 bb = __float22bfloat162_rn(make_float2(x, y));
        *reinterpret_cast<unsigned*>(&Wt[c][k0]) = *reinterpret_cast<unsigned*>(&bb);
    }
    __syncthreads();

    const int l    = t & 63;
    const int wv   = t >> 6;
    const int cl   = l & 15;          // col-in-tile / row-in-tile for A
    const int kg   = l >> 4;          // 0..3 k-group
    const int rbase = blockIdx.x * 64 + wv * 16;
    const int r    = rbase + cl;
    const int rld  = min(r, N - 1);
    const float4* hrow = reinterpret_cast<const float4*>(h) + (size_t)rld * (IN_F / 4);

    f32x4 acc[4];
#pragma unroll
    for (int nt = 0; nt < 4; ++nt) acc[nt] = (f32x4){0.f, 0.f, 0.f, 0.f};

#pragma unroll
    for (int ks = 0; ks < 8; ++ks) {
        float4 a0 = hrow[ks * 8 + kg * 2];
        float4 a1 = hrow[ks * 8 + kg * 2 + 1];
        short8 af = cvt8(a0, a1);
#pragma unroll
        for (int nt = 0; nt < 4; ++nt) {
            short8 bf = *reinterpret_cast<const short8*>(&Wt[nt * 16 + cl][ks * 32 + kg * 8]);
            acc[nt] = __builtin_amdgcn_mfma_f32_16x16x32_bf16(af, bf, acc[nt], 0, 0, 0);
        }
    }

    // D: col = lane&15, row = (lane>>4)*4 + reg
#pragma unroll
    for (int nt = 0; nt < 4; ++nt)
#pragma unroll
        for (int rg = 0; rg < 4; ++rg) {
            int rr = rbase + kg * 4 + rg;
            if (rr < N)
                hp[(size_t)rr * OU_F + nt * 16 + cl] = acc[nt][rg];
        }
}

// ---------------- bucket histogram ----------------
__global__ void __launch_bounds__(256)
hist_kernel(const int* __restrict__ col, int* __restrict__ bcnt, int E, int NB)
{
    __shared__ int lh[512];
    const int t = threadIdx.x;
    lh[t] = 0; lh[t + 256] = 0;
    __syncthreads();
    const int n4 = E >> 2;
    const int4* c4 = (const int4*)col;
    for (int i = blockIdx.x * 256 + t; i < n4; i += gridDim.x * 256) {
        int4 v = c4[i];
        atomicAdd(&lh[v.x >> BSHIFT], 1);
        atomicAdd(&lh[v.y >> BSHIFT], 1);
        atomicAdd(&lh[v.z >> BSHIFT], 1);
        atomicAdd(&lh[v.w >> BSHIFT], 1);
    }
    if (blockIdx.x == 0)
        for (int e = (n4 << 2) + t; e < E; e += 256)
            atomicAdd(&lh[col[e] >> BSHIFT], 1);
    __syncthreads();
    for (int i = t; i < NB; i += 256)
        if (lh[i]) atomicAdd(&bcnt[i], lh[i]);
}

// ---------------- exclusive scan of <=512 bucket counts (1 block) ----------------
__global__ void __launch_bounds__(256)
scan_kernel(const int* __restrict__ bcnt, int* __restrict__ boffs,
            int* __restrict__ bcursor, int NB)
{
    __shared__ int c[512];
    __shared__ int s[256];
    const int t = threadIdx.x;
    c[t]       = (t < NB)       ? bcnt[t] : 0;
    c[t + 256] = (t + 256 < NB) ? bcnt[t + 256] : 0;
    __syncthreads();
    s[t] = c[2 * t] + c[2 * t + 1];
    __syncthreads();
    for (int d = 1; d < 256; d <<= 1) {
        int v = (t >= d) ? s[t - d] : 0;
        __syncthreads();
        s[t] += v;
        __syncthreads();
    }
    int excl = (t > 0) ? s[t - 1] : 0;
    int e0 = excl;
    int e1 = excl + c[2 * t];
    if (2 * t < NB)     { boffs[2 * t]     = e0; bcursor[2 * t]     = e0; }
    if (2 * t + 1 < NB) { boffs[2 * t + 1] = e1; bcursor[2 * t + 1] = e1; }
    if (t == 255) boffs[NB] = s[255];
}

// ---------------- partition: counting-sort edges into buckets, coalesced writes ----------------
__global__ void __launch_bounds__(256)
partition_kernel(const int* __restrict__ row, const int* __restrict__ col,
                 const float* __restrict__ vals, int* __restrict__ bcursor,
                 int2* __restrict__ epk, int E, int NB)
{
    __shared__ int  hist[512];
    __shared__ int  X[512];        // local excl scan, then running cursor
    __shared__ int  gshift[512];   // global base - local base
    __shared__ int  s[256];
    __shared__ int2 stage[CHUNK];  // 32 KB
    __shared__ int  gpos[CHUNK];   // 16 KB

    const int t = threadIdx.x;
    const int base = blockIdx.x * CHUNK;
    const int n = min(CHUNK, E - base);

    hist[t] = 0; hist[t + 256] = 0;
    __syncthreads();

#pragma unroll
    for (int k = 0; k < 16; ++k) {
        int i = t + k * 256;
        if (i < n) atomicAdd(&hist[col[base + i] >> BSHIFT], 1);
    }
    __syncthreads();

    s[t] = hist[2 * t] + hist[2 * t + 1];
    __syncthreads();
    for (int d = 1; d < 256; d <<= 1) {
        int v = (t >= d) ? s[t - d] : 0;
        __syncthreads();
        s[t] += v;
        __syncthreads();
    }
    int excl = (t > 0) ? s[t - 1] : 0;
    X[2 * t]     = excl;
    X[2 * t + 1] = excl + hist[2 * t];
    __syncthreads();

    for (int i = t; i < NB; i += 256) {
        int hcnt = hist[i];
        int g = hcnt ? atomicAdd(&bcursor[i], hcnt) : 0;
        gshift[i] = g - X[i];
    }
    __syncthreads();

#pragma unroll
    for (int k = 0; k < 16; ++k) {
        int i = t + k * 256;
        if (i < n) {
            int e  = base + i;
            int cv = col[e];
            int b  = cv >> BSHIFT;
            int r  = atomicAdd(&X[b], 1);
            unsigned pk = (unsigned)row[e] | ((unsigned)(cv & (BKN - 1)) << 17);
            stage[r] = make_int2((int)pk, __float_as_int(vals[e]));
            gpos[r]  = gshift[b] + r;
        }
    }
    __syncthreads();

#pragma unroll
    for (int k = 0; k < 16; ++k) {
        int i = t + k * 256;
        if (i < n) epk[gpos[i]] = stage[i];   // runs of consecutive addresses
    }
}

// ---------------- within-bucket counting sort by node + CSR offsets ----------------
__global__ void __launch_bounds__(256)
csr_kernel(const int2* __restrict__ epk, const int* __restrict__ boffs,
           int2* __restrict__ epk2, int* __restrict__ node_offs,
           int N, int NB)
{
    __shared__ int  cnt[BKN];
    __shared__ int  sc[BKN];
    __shared__ int  cur[BKN];
    __shared__ int2 stage[STAGE_CAP];   // 32 KB
    const int t = threadIdx.x;
    const int b = blockIdx.x;
    const int s = boffs[b], e = boffs[b + 1];
    const int n = e - s;
    const int node0 = b << BSHIFT;

    if (t < BKN) cnt[t] = 0;
    __syncthreads();
    for (int i = t; i < n; i += 256)
        atomicAdd(&cnt[((unsigned)epk[s + i].x) >> 17], 1);
    __syncthreads();

    if (t < BKN) sc[t] = cnt[t];
    __syncthreads();
    for (int d = 1; d < BKN; d <<= 1) {
        int v = 0;
        if (t < BKN && t >= d) v = sc[t - d];
        __syncthreads();
        if (t < BKN) sc[t] += v;
        __syncthreads();
    }
    if (t < BKN) {
        int excl = sc[t] - cnt[t];
        cur[t] = excl;
        int node = node0 + t;
        if (node < N) node_offs[node] = s + excl;
    }
    if (b == NB - 1 && t == 0) node_offs[N] = e;
    __syncthreads();

    if (n <= STAGE_CAP) {
        for (int i = t; i < n; i += 256) {
            int2 r = epk[s + i];
            int pos = atomicAdd(&cur[((unsigned)r.x) >> 17], 1);
            stage[pos] = r;
        }
        __syncthreads();
        for (int i = t; i < n; i += 256)
            epk2[s + i] = stage[i];           // fully coalesced
    } else {
        for (int i = t; i < n; i += 256) {
            int2 r = epk[s + i];
            int pos = atomicAdd(&cur[((unsigned)r.x) >> 17], 1);
            epk2[s + pos] = r;
        }
    }
}

// ---------------- gather: one wave per destination node, no atomics ----------------
__global__ void __launch_bounds__(256)
gather_kernel(const float* __restrict__ hp, const int* __restrict__ node_offs,
              const int2* __restrict__ epk2, float* __restrict__ out, int N)
{
    int wid  = (int)((blockIdx.x * 256u + threadIdx.x) >> 6);   // node id
    int lane = threadIdx.x & 63;                                 // feature id
    if (wid >= N) return;
    int s = node_offs[wid], e = node_offs[wid + 1];
    float acc = 0.f;
    for (int base = s; base < e; base += 64) {
        int n = min(64, e - base);
        int2 m = make_int2(0, 0);
        if (lane < n) m = epk2[base + lane];
        int j = 0;
        for (; j + 4 <= n; j += 4) {
            unsigned r0 = (unsigned)__shfl(m.x, j)     & 0x1FFFFu;
            unsigned r1 = (unsigned)__shfl(m.x, j + 1) & 0x1FFFFu;
            unsigned r2 = (unsigned)__shfl(m.x, j + 2) & 0x1FFFFu;
            unsigned r3 = (unsigned)__shfl(m.x, j + 3) & 0x1FFFFu;
            float v0 = __int_as_float(__shfl(m.y, j));
            float v1 = __int_as_float(__shfl(m.y, j + 1));
            float v2 = __int_as_float(__shfl(m.y, j + 2));
            float v3 = __int_as_float(__shfl(m.y, j + 3));
            float x0 = hp[((size_t)r0 << 6) + lane];
            float x1 = hp[((size_t)r1 << 6) + lane];
            float x2 = hp[((size_t)r2 << 6) + lane];
            float x3 = hp[((size_t)r3 << 6) + lane];
            acc = fmaf(v0, x0, acc);
            acc = fmaf(v1, x1, acc);
            acc = fmaf(v2, x2, acc);
            acc = fmaf(v3, x3, acc);
        }
        for (; j < n; ++j) {
            unsigned r = (unsigned)__shfl(m.x, j) & 0x1FFFFu;
            float    v = __int_as_float(__shfl(m.y, j));
            acc = fmaf(v, hp[((size_t)r << 6) + lane], acc);
        }
    }
    out[(size_t)wid * OU_F + lane] = acc;
}

// ---------------- fallback (atomic scatter) ----------------
__global__ void __launch_bounds__(256)
scatter_kernel(const float* __restrict__ hp, const int* __restrict__ row,
               const int* __restrict__ col, const float* __restrict__ vals,
               float* __restrict__ out, int E)
{
    unsigned int gid = blockIdx.x * 256u + threadIdx.x;
    int e = (int)(gid >> 6);
    if (e >= E) return;
    int f = (int)(gid & 63u);
    int r = row[e], c = col[e];
    float m = vals[e] * hp[(size_t)r * OU_F + f];
    __hip_atomic_fetch_add(&out[(size_t)c * OU_F + f], m,
                           __ATOMIC_RELAXED, __HIP_MEMORY_SCOPE_AGENT);
}

extern "C" void kernel_launch(void* const* d_in, const int* in_sizes, int n_in,
                              void* d_out, int out_size, void* d_ws, size_t ws_size,
                              hipStream_t stream)
{
    const float* h    = (const float*)d_in[0];
    const float* W    = (const float*)d_in[1];
    const int*   row  = (const int*)d_in[2];
    const int*   col  = (const int*)d_in[3];
    const float* vals = (const float*)d_in[4];
    float*       out  = (float*)d_out;

    const int N = in_sizes[0] / IN_F;
    const int E = in_sizes[2];
    const int NB = (N + BKN - 1) / BKN;

    char*  ws  = (char*)d_ws;
    size_t off = 0;
    auto alloc = [&](size_t bytes) -> char* {
        char* p = ws + off;
        off = (off + bytes + 255) & ~(size_t)255;
        return p;
    };
    float* hp        = (float*)alloc((size_t)N * OU_F * 4);
    int*   bcnt      = (int*)  alloc((size_t)NB * 4);
    int*   boffs     = (int*)  alloc((size_t)(NB + 1) * 4);
    int*   bcursor   = (int*)  alloc((size_t)NB * 4);
    int*   node_offs = (int*)  alloc((size_t)(N + 1) * 4);
    int2*  epk       = (int2*) alloc((size_t)E * 8);
    int2*  epk2      = (int2*) alloc((size_t)E * 8);
    const bool fits = (off <= ws_size) && (NB <= 512) && (N < 131072);

    const int ntiles = (N + 63) / 64;
    gemm_mfma_kernel<<<ntiles, 256, 0, stream>>>(h, W, hp, N);

    if (fits) {
        hipMemsetAsync(bcnt, 0, (size_t)NB * 4, stream);
        hist_kernel<<<256, 256, 0, stream>>>(col, bcnt, E, NB);
        scan_kernel<<<1, 256, 0, stream>>>(bcnt, boffs, bcursor, NB);
        partition_kernel<<<(E + CHUNK - 1) / CHUNK, 256, 0, stream>>>(
            row, col, vals, bcursor, epk, E, NB);
        csr_kernel<<<NB, 256, 0, stream>>>(epk, boffs, epk2, node_offs, N, NB);
        gather_kernel<<<(N + 3) / 4, 256, 0, stream>>>(hp, node_offs, epk2, out, N);
    } else {
        hipMemsetAsync(d_out, 0, (size_t)out_size * sizeof(float), stream);
        unsigned long long total = (unsigned long long)E * 64ull;
        unsigned int sgrid = (unsigned int)((total + 255ull) / 256ull);
        scatter_kernel<<<sgrid, 256, 0, stream>>>(hp, row, col, vals, out, E);
    }
}